// Round 19
// baseline (168.215 us; speedup 1.0000x reference)
//
#include <hip/hip_runtime.h>
#include <hip/hip_bf16.h>
#include <math.h>

typedef __bf16 bf16;
typedef __bf16 bf16x8 __attribute__((ext_vector_type(8)));
typedef __bf16 bf16x4 __attribute__((ext_vector_type(4)));
typedef float f32x4 __attribute__((ext_vector_type(4)));
typedef float f32x16 __attribute__((ext_vector_type(16)));

#define T_SEQ 1024
#define NH 16
#define HD 64
#define DM 1024
#define LOG2E 1.44269504088896f

__device__ __forceinline__ f32x16 mfma32(bf16x8 a, bf16x8 b, f32x16 c) {
  return __builtin_amdgcn_mfma_f32_32x32x16_bf16(a, b, c, 0, 0, 0);
}

__device__ __forceinline__ void gl_lds16(const bf16* g, bf16* l) {
  __builtin_amdgcn_global_load_lds(
      (const __attribute__((address_space(1))) void*)(g),
      (__attribute__((address_space(3))) void*)(l), 16, 0, 0);
}
__device__ __forceinline__ void gl_lds4(const float* g, float* l) {
  __builtin_amdgcn_global_load_lds(
      (const __attribute__((address_space(1))) void*)(g),
      (__attribute__((address_space(3))) void*)(l), 4, 0, 0);
}

// ---------------- bias table: table[h][d] in exp2 (log2e-scaled) domain ----------------
__global__ void hope_bias_kernel(const float* __restrict__ pi, float* __restrict__ table) {
  int idx = blockIdx.x * blockDim.x + threadIdx.x;
  if (idx >= 1024 * NH) return;
  int h = idx >> 10, d = idx & 1023;
  float s = 0.f;
  if (h < 8) {
    int p0 = h * 32;
    for (int t = 0; t < 32; ++t) {
      float f = expf(-(float)(p0 + t) * (9.210340371976184f / 512.0f));
      float theta = (float)d * f;
      s += cosf(theta) + sinf(theta);
    }
  } else {
    int p0 = (h - 8) * 32;
    for (int t = 0; t < 32; ++t)
      s += pi[(p0 + t) * 2] + pi[(p0 + t) * 2 + 1];
  }
  table[h * 1024 + d] = s * LOG2E;
}

// ---------------- merged f32 -> bf16 convert ----------------
__global__ void cvt3_kernel(const float* __restrict__ a, bf16* __restrict__ oa, int na,
                            const float* __restrict__ b, bf16* __restrict__ ob, int nb,
                            const float* __restrict__ c, bf16* __restrict__ oc, int nc) {
  int i = (blockIdx.x * blockDim.x + threadIdx.x) * 4;
  const float* src; bf16* dst; int off;
  if (i < na) { src = a; dst = oa; off = i; }
  else if (i < na + nb) { src = b; dst = ob; off = i - na; }
  else if (i < na + nb + nc) { src = c; dst = oc; off = i - na - nb; }
  else return;
  float4 v = *reinterpret_cast<const float4*>(src + off);
  bf16x4 o;
  o[0] = (bf16)v.x; o[1] = (bf16)v.y; o[2] = (bf16)v.z; o[3] = (bf16)v.w;
  *reinterpret_cast<bf16x4*>(dst + off) = o;
}

// ================= 256x128 GEMM, BK=32, 5-buffer deep pipeline, 120KB LDS =================
// Tile t stages tile t+4 (window = 4 tiles); steady-state s_waitcnt vmcnt(9) per tile
// (12 outstanding, waits only for the oldest tile's 3 loads). One barrier per K-tile.
// Stage layout: LDS (row, cg) holds global slot cg ^ f(row), f(r) = (r&3)^((r>>2)&3).
// Wave 4x2 grid, wave-tile 64x64 = 2x2 mfma32; per K-tile: 8 ds_read_b128 + 8 mfma32.

__device__ __forceinline__ void stageA32(const bf16* __restrict__ G, int gr0, int t,
                                         bf16* D, int tid) {
  const int k0 = t * 32;
#pragma unroll
  for (int c = 0; c < 2; ++c) {
    const int idx = c * 512 + tid;
    const int row = idx >> 2, cg = idx & 3;
    const int scg = cg ^ (row & 3) ^ ((row >> 2) & 3);
    gl_lds16(&G[(size_t)(gr0 + row) * 1024 + k0 + scg * 8],
             D + (size_t)(c * 512 + (tid & 448)) * 8);
  }
}
__device__ __forceinline__ void stageB32(const bf16* __restrict__ G, int gr0, int t,
                                         bf16* D, int tid) {
  const int k0 = t * 32;
  const int row = tid >> 2, cg = tid & 3;
  const int scg = cg ^ (row & 3) ^ ((row >> 2) & 3);
  gl_lds16(&G[(size_t)(gr0 + row) * 1024 + k0 + scg * 8],
           D + (size_t)(tid & 448) * 8);
}

template<bool STG, int WAIT>
__device__ __forceinline__ void ktile32(bf16* SA, bf16* SDn,
    const bf16* __restrict__ A, const bf16* __restrict__ Bt,
    int m0, int n0, int t2,
    f32x16 (&acc)[2][2], int tid, int wr, int wc, int ql, int hi) {
  bf16* SB = SA + 8192;
  const int f = (ql & 3) ^ ((ql >> 2) & 3);
  bf16x8 aF[2][2], bF[2][2];
#pragma unroll
  for (int bi = 0; bi < 2; ++bi)
#pragma unroll
    for (int st = 0; st < 2; ++st) {
      const int slot = (st * 2 + hi) ^ f;
      aF[bi][st] = *reinterpret_cast<const bf16x8*>(
          &SA[(wr * 64 + bi * 32 + ql) * 32 + slot * 8]);
      bF[bi][st] = *reinterpret_cast<const bf16x8*>(
          &SB[(wc * 64 + bi * 32 + ql) * 32 + slot * 8]);
    }
  if (STG) {
    stageA32(A, m0, t2, SDn, tid);
    stageB32(Bt, n0, t2, SDn + 8192, tid);
  }
#pragma unroll
  for (int st = 0; st < 2; ++st)
#pragma unroll
    for (int bi = 0; bi < 2; ++bi)
#pragma unroll
      for (int bj = 0; bj < 2; ++bj)
        acc[bi][bj] = mfma32(aF[bi][st], bF[bj][st], acc[bi][bj]);
  if (WAIT == 9)      asm volatile("s_waitcnt vmcnt(9)" ::: "memory");
  else if (WAIT == 6) asm volatile("s_waitcnt vmcnt(6)" ::: "memory");
  else if (WAIT == 3) asm volatile("s_waitcnt vmcnt(3)" ::: "memory");
  else if (WAIT == 0) asm volatile("s_waitcnt vmcnt(0)" ::: "memory");
  __builtin_amdgcn_s_barrier();
}

__device__ __forceinline__ void gemmN_mainloop(
    bf16* S, const bf16* __restrict__ A, const bf16* __restrict__ Bt,
    int m0, int n0, f32x16 (&acc)[2][2],
    int tid, int wr, int wc, int ql, int hi) {
  bf16* P0 = S;
  bf16* P1 = S + 12288;
  bf16* P2 = S + 24576;
  bf16* P3 = S + 36864;
  bf16* P4 = S + 49152;
  // prologue: stage tiles 0..3 (12 loads), wait for tile 0 (oldest 3)
  stageA32(A, m0, 0, P0, tid); stageB32(Bt, n0, 0, P0 + 8192, tid);
  stageA32(A, m0, 1, P1, tid); stageB32(Bt, n0, 1, P1 + 8192, tid);
  stageA32(A, m0, 2, P2, tid); stageB32(Bt, n0, 2, P2 + 8192, tid);
  stageA32(A, m0, 3, P3, tid); stageB32(Bt, n0, 3, P3 + 8192, tid);
  asm volatile("s_waitcnt vmcnt(9)" ::: "memory");
  __builtin_amdgcn_s_barrier();
  // t = 0..24 in 5 groups of 5 (buf = t%5), staging t+4
#pragma unroll 1
  for (int g5 = 0; g5 < 5; ++g5) {
    const int t = g5 * 5;
    ktile32<true, 9>(P0, P4, A, Bt, m0, n0, t + 4, acc, tid, wr, wc, ql, hi);
    ktile32<true, 9>(P1, P0, A, Bt, m0, n0, t + 5, acc, tid, wr, wc, ql, hi);
    ktile32<true, 9>(P2, P1, A, Bt, m0, n0, t + 6, acc, tid, wr, wc, ql, hi);
    ktile32<true, 9>(P3, P2, A, Bt, m0, n0, t + 7, acc, tid, wr, wc, ql, hi);
    ktile32<true, 9>(P4, P3, A, Bt, m0, n0, t + 8, acc, tid, wr, wc, ql, hi);
  }
  // t = 25..27 stage 29..31; then drain 28..31
  ktile32<true, 9>(P0, P4, A, Bt, m0, n0, 29, acc, tid, wr, wc, ql, hi);
  ktile32<true, 9>(P1, P0, A, Bt, m0, n0, 30, acc, tid, wr, wc, ql, hi);
  ktile32<true, 9>(P2, P1, A, Bt, m0, n0, 31, acc, tid, wr, wc, ql, hi);
  ktile32<false, 6>(P3, P2, A, Bt, m0, n0, 0, acc, tid, wr, wc, ql, hi);
  ktile32<false, 3>(P4, P3, A, Bt, m0, n0, 0, acc, tid, wr, wc, ql, hi);
  ktile32<false, 0>(P0, P4, A, Bt, m0, n0, 0, acc, tid, wr, wc, ql, hi);
  ktile32<false, -1>(P1, P0, A, Bt, m0, n0, 0, acc, tid, wr, wc, ql, hi);
}

// ---------------- QKV projection: grid 768 = 3 exact rounds (1 block/CU) ----------------
__global__ __launch_bounds__(512, 2) void gemm_qkv8_kernel(
    const bf16* __restrict__ xb, const bf16* __restrict__ wb,
    const float* __restrict__ bias,
    bf16* __restrict__ Q, bf16* __restrict__ K, bf16* __restrict__ Vt) {
  extern __shared__ bf16 S[];
  const int tid = threadIdx.x;
  const int lane = tid & 63, wave = tid >> 6;
  const int wr = wave >> 1, wc = wave & 1;
  const int ql = lane & 31, hi = lane >> 5;
  const int wg = blockIdx.x;
  const int xcd = wg & 7, r = wg >> 3;
  const int sc = r / 48, t = r % 48;
  const int mi_ = t / 12, ni_ = sc * 12 + (t % 12);
  const int m0 = (xcd * 4 + mi_) * 256;
  const int n0 = ni_ * 128;

  f32x16 acc[2][2];
#pragma unroll
  for (int i = 0; i < 2; ++i)
#pragma unroll
    for (int j = 0; j < 2; ++j)
#pragma unroll
      for (int r4 = 0; r4 < 16; ++r4) acc[i][j][r4] = 0.f;

  gemmN_mainloop(S, xb, wb, m0, n0, acc, tid, wr, wc, ql, hi);

  const int c3 = n0 >> 10;
  const int bb = m0 >> 10;
#pragma unroll
  for (int bi = 0; bi < 2; ++bi) {
#pragma unroll
    for (int bj = 0; bj < 2; ++bj) {
      const int col = n0 + wc * 64 + bj * 32 + ql;
      const float bv = bias[col];
      const int hh = (col & 1023) >> 6;
      const int dd = col & 63;
      const size_t bhh = (size_t)(bb * NH + hh);
#pragma unroll
      for (int g4 = 0; g4 < 4; ++g4) {
        const int t0 = (m0 & 1023) + wr * 64 + bi * 32 + 8 * g4 + 4 * hi;
        if (c3 == 2) {
          bf16x4 pk;
#pragma unroll
          for (int rr = 0; rr < 4; ++rr) pk[rr] = (bf16)(acc[bi][bj][g4 * 4 + rr] + bv);
          *reinterpret_cast<bf16x4*>(&Vt[(bhh * HD + dd) * T_SEQ + t0]) = pk;
        } else {
          bf16* dst = (c3 == 0) ? Q : K;
#pragma unroll
          for (int rr = 0; rr < 4; ++rr)
            dst[(bhh * T_SEQ + t0 + rr) * HD + dd] = (bf16)(acc[bi][bj][g4 * 4 + rr] + bv);
        }
      }
    }
  }
}

// ---------------- output projection: grid 256 = 1 exact round ----------------
__global__ __launch_bounds__(512, 2) void gemm_proj8_kernel(
    const bf16* __restrict__ Ob, const bf16* __restrict__ wb,
    const float* __restrict__ bias, float* __restrict__ out) {
  extern __shared__ bf16 S[];
  const int tid = threadIdx.x;
  const int lane = tid & 63, wave = tid >> 6;
  const int wr = wave >> 1, wc = wave & 1;
  const int ql = lane & 31, hi = lane >> 5;
  const int wg = blockIdx.x;
  const int L = (wg & 7) * 32 + (wg >> 3);
  const int n0 = (L % 8) * 128;
  const int m0 = (L / 8) * 256;

  f32x16 acc[2][2];
#pragma unroll
  for (int i = 0; i < 2; ++i)
#pragma unroll
    for (int j = 0; j < 2; ++j)
#pragma unroll
      for (int r4 = 0; r4 < 16; ++r4) acc[i][j][r4] = 0.f;

  gemmN_mainloop(S, Ob, wb, m0, n0, acc, tid, wr, wc, ql, hi);

#pragma unroll
  for (int bi = 0; bi < 2; ++bi) {
#pragma unroll
    for (int bj = 0; bj < 2; ++bj) {
      const int col = n0 + wc * 64 + bj * 32 + ql;
      const float bv = bias[col];
#pragma unroll
      for (int g4 = 0; g4 < 4; ++g4) {
        const int row = m0 + wr * 64 + bi * 32 + 8 * g4 + 4 * hi;
#pragma unroll
        for (int rr = 0; rr < 4; ++rr)
          out[(size_t)(row + rr) * DM + col] = acc[bi][bj][g4 * 4 + rr] + bv;
      }
    }
  }
}

// ---------------- causal flash attention (R18 form: LDS bias window, frozen) ----------------
__device__ __forceinline__ uint2 pk4f(float a, float b, float c, float d) {
  bf16x4 v; v[0] = (bf16)a; v[1] = (bf16)b; v[2] = (bf16)c; v[3] = (bf16)d;
  uint2 u; __builtin_memcpy(&u, &v, 8); return u;
}

__global__ __launch_bounds__(256) void attn_kernel(
    const bf16* __restrict__ Q, const bf16* __restrict__ K,
    const bf16* __restrict__ Vt, const float* __restrict__ table,
    bf16* __restrict__ O)
{
  __shared__ bf16 Ks[2][64 * 64];
  __shared__ bf16 Vs[2][64 * 64];
  __shared__ float win[2][256];

  const int tid = threadIdx.x;
  const int lane = tid & 63;
  const int wq = tid >> 6;
  const int ql = lane & 31;
  const int hi = lane >> 5;
  const int ch = lane & 7;

  const int w = blockIdx.x;
  const int xcd = w & 7, idx = w >> 3;
  const int bh = xcd * 16 + (idx & 15);
  const int qt = 7 - (idx >> 4);
  const int h = bh & 15, b = bh >> 4;
  const int q0 = qt * 128;
  const int nkt = 2 * qt + 2;

  const bf16* Qp = Q + (size_t)bh * (T_SEQ * HD);
  const bf16* Kp = K + (size_t)bh * (T_SEQ * HD);
  const bf16* Vp = Vt + (size_t)bh * (HD * T_SEQ);
  const float* tb = table + h * 1024;

  const int qg = q0 + wq * 32 + ql;

  bf16x8 qf[4];
#pragma unroll
  for (int cs = 0; cs < 4; ++cs)
    qf[cs] = *reinterpret_cast<const bf16x8*>(&Qp[(size_t)qg * HD + cs * 16 + hi * 8]);

  f32x16 o0, o1;
#pragma unroll
  for (int r = 0; r < 16; ++r) { o0[r] = 0.f; o1[r] = 0.f; }
  float m_ = -1e30f, l_ = 0.f;

  const int srow = wq * 16;
  const int lrow = lane >> 3;

  auto stage = [&](int kt, int buf) {
#pragma unroll
    for (int i = 0; i < 2; ++i) {
      const int r0 = srow + i * 8;
      const int row = r0 + lrow;
      gl_lds16(&Kp[(size_t)(kt * 64 + row) * HD + 8 * (ch ^ (row & 7))],
               &Ks[buf][r0 * 64]);
      gl_lds16(&Vp[(size_t)row * T_SEQ + kt * 64 + 8 * (ch ^ (row & 7))],
               &Vs[buf][r0 * 64]);
    }
    gl_lds4(&tb[q0 - kt * 64 - 96 + tid], &win[buf][wq * 64]);
  };

  stage(0, 0);
  __syncthreads();

  for (int kt = 0; kt < nkt; ++kt) {
    const int buf = kt & 1;

    const float* wp = &win[buf][wq * 32 + ql - 4 * hi];
    float bias0[16], bias1[16];
#pragma unroll
    for (int r = 0; r < 16; ++r) {
      const int cr = (r & 3) + 8 * (r >> 2);
      bias0[r] = wp[96 - cr];
      bias1[r] = wp[64 - cr];
    }

    if (kt + 1 < nkt) stage(kt + 1, buf ^ 1);

    f32x16 st0, st1;
#pragma unroll
    for (int r = 0; r < 16; ++r) { st0[r] = 0.f; st1[r] = 0.f; }
    __builtin_amdgcn_s_setprio(1);
#pragma unroll
    for (int cs = 0; cs < 4; ++cs) {
      bf16x8 k0 = *reinterpret_cast<const bf16x8*>(&Ks[buf][ql * 64 + (((2 * cs + hi) ^ ch) * 8)]);
      bf16x8 k1 = *reinterpret_cast<const bf16x8*>(&Ks[buf][(32 + ql) * 64 + (((2 * cs + hi) ^ ch) * 8)]);
      st0 = mfma32(k0, qf[cs], st0);
      st1 = mfma32(k1, qf[cs], st1);
    }
    __builtin_amdgcn_s_setprio(0);

    const float SCALE2 = 0.125f * LOG2E;
    const int C2 = qg - kt * 64 - 4 * hi;
#pragma unroll
    for (int r = 0; r < 16; ++r) {
      const int cr = (r & 3) + 8 * (r >> 2);
      float v0 = (cr <= C2)      ? st0[r] * SCALE2 + bias0[r] : -1e30f;
      float v1 = (cr + 32 <= C2) ? st1[r] * SCALE2 + bias1[r] : -1e30f;
      st0[r] = v0; st1[r] = v1;
    }
    float t8[8];
#pragma unroll
    for (int j = 0; j < 8; ++j)
      t8[j] = fmaxf(fmaxf(st0[j], st0[j + 8]), fmaxf(st1[j], st1[j + 8]));
#pragma unroll
    for (int j = 0; j < 4; ++j) t8[j] = fmaxf(t8[j], t8[j + 4]);
    float pmax = fmaxf(fmaxf(t8[0], t8[1]), fmaxf(t8[2], t8[3]));
    pmax = fmaxf(pmax, __shfl_xor(pmax, 32));
    const float mnew = fmaxf(m_, pmax);
    const float corr = exp2f(m_ - mnew);
    m_ = mnew;
    float s0 = 0.f, s1 = 0.f;
#pragma unroll
    for (int r = 0; r < 16; ++r) {
      float e0 = exp2f(st0[r] - mnew); st0[r] = e0; s0 += e0;
      float e1 = exp2f(st1[r] - mnew); st1[r] = e1; s1 += e1;
    }
    float sum = s0 + s1;
    sum += __shfl_xor(sum, 32);
    l_ = l_ * corr + sum;
#pragma unroll
    for (int r = 0; r < 16; ++r) { o0[r] *= corr; o1[r] *= corr; }

    auto mkfrag = [&](const f32x16& p, int u) -> bf16x8 {
      uint2 A = pk4f(p[8 * u + 0], p[8 * u + 1], p[8 * u + 2], p[8 * u + 3]);
      uint2 B = pk4f(p[8 * u + 4], p[8 * u + 5], p[8 * u + 6], p[8 * u + 7]);
      uint2 send; send.x = hi ? A.x : B.x; send.y = hi ? A.y : B.y;
      uint2 recv; recv.x = __shfl_xor(send.x, 32); recv.y = __shfl_xor(send.y, 32);
      uint4 wf;
      wf.x = hi ? recv.x : A.x;  wf.y = hi ? recv.y : A.y;
      wf.z = hi ? B.x : recv.x;  wf.w = hi ? B.y : recv.y;
      bf16x8 fr; __builtin_memcpy(&fr, &wf, 16); return fr;
    };
    bf16x8 f0 = mkfrag(st0, 0);
    bf16x8 f1 = mkfrag(st0, 1);
    bf16x8 f2 = mkfrag(st1, 0);
    bf16x8 f3 = mkfrag(st1, 1);

    __builtin_amdgcn_s_setprio(1);
#pragma unroll
    for (int s = 0; s < 4; ++s) {
      bf16x8 vf0 = *reinterpret_cast<const bf16x8*>(&Vs[buf][ql * 64 + (((2 * s + hi) ^ ch) * 8)]);
      bf16x8 vf1 = *reinterpret_cast<const bf16x8*>(&Vs[buf][(32 + ql) * 64 + (((2 * s + hi) ^ ch) * 8)]);
      bf16x8 pf = (s == 0) ? f0 : (s == 1) ? f1 : (s == 2) ? f2 : f3;
      o0 = mfma32(vf0, pf, o0);
      o1 = mfma32(vf1, pf, o1);
    }
    __builtin_amdgcn_s_setprio(0);

    __syncthreads();
  }

  const float inv = 1.0f / l_;
  const size_t base = ((size_t)(b * T_SEQ + qg)) * DM + h * HD;
#pragma unroll
  for (int r4 = 0; r4 < 4; ++r4) {
    bf16x4 p0, p1;
#pragma unroll
    for (int j = 0; j < 4; ++j) {
      p0[j] = (bf16)(o0[r4 * 4 + j] * inv);
      p1[j] = (bf16)(o1[r4 * 4 + j] * inv);
    }
    *reinterpret_cast<bf16x4*>(&O[base + 8 * r4 + 4 * hi]) = p0;
    *reinterpret_cast<bf16x4*>(&O[base + 32 + 8 * r4 + 4 * hi]) = p1;
  }
}

extern "C" void kernel_launch(void* const* d_in, const int* in_sizes, int n_in,
                              void* d_out, int out_size, void* d_ws, size_t ws_size,
                              hipStream_t stream) {
  const float* x      = (const float*)d_in[0];
  const float* w_qkv  = (const float*)d_in[1];
  const float* b_qkv  = (const float*)d_in[2];
  const float* w_proj = (const float*)d_in[3];
  const float* b_proj = (const float*)d_in[4];
  const float* pos_in = (const float*)d_in[5];
  float* out = (float*)d_out;

  char* ws = (char*)d_ws;
  bf16* xb     = (bf16*)(ws);                         // 16 MB (reused as Ob)
  bf16* wqkvb  = (bf16*)(ws + 16777216);              //  6 MB
  bf16* wprojb = (bf16*)(ws + 23068672);              //  2 MB
  bf16* Qb     = (bf16*)(ws + 25165824);              // 16 MB
  bf16* Kb     = (bf16*)(ws + 41943040);              // 16 MB
  bf16* Vtb    = (bf16*)(ws + 58720256);              // 16 MB
  float* table = (float*)(ws + 75497472);             // 64 KB
  bf16* Ob = xb;

  static bool attr_done = false;
  if (!attr_done) {
    hipFuncSetAttribute((const void*)gemm_qkv8_kernel,
                        hipFuncAttributeMaxDynamicSharedMemorySize, 122880);
    hipFuncSetAttribute((const void*)gemm_proj8_kernel,
                        hipFuncAttributeMaxDynamicSharedMemorySize, 122880);
    attr_done = true;
  }

  const int nx = 8 * T_SEQ * DM, nwq = 3 * DM * DM, nwp = DM * DM;
  hope_bias_kernel<<<64, 256, 0, stream>>>(pos_in, table);
  cvt3_kernel<<<(nx + nwq + nwp) / 1024, 256, 0, stream>>>(
      x, xb, nx, w_qkv, wqkvb, nwq, w_proj, wprojb, nwp);

  gemm_qkv8_kernel<<<768, 512, 122880, stream>>>(xb, wqkvb, b_qkv, Qb, Kb, Vtb);
  attn_kernel<<<1024, 256, 0, stream>>>(Qb, Kb, Vtb, table, Ob);
  gemm_proj8_kernel<<<256, 512, 122880, stream>>>(Ob, wprojb, b_proj, out);
}

// Round 20
// 155.123 us; speedup vs baseline: 1.0844x; 1.0844x over previous
//
#include <hip/hip_runtime.h>
#include <hip/hip_bf16.h>
#include <math.h>

typedef __bf16 bf16;
typedef __bf16 bf16x8 __attribute__((ext_vector_type(8)));
typedef __bf16 bf16x4 __attribute__((ext_vector_type(4)));
typedef float f32x4 __attribute__((ext_vector_type(4)));
typedef float f32x16 __attribute__((ext_vector_type(16)));

#define T_SEQ 1024
#define NH 16
#define HD 64
#define DM 1024
#define LOG2E 1.44269504088896f

__device__ __forceinline__ f32x16 mfma32(bf16x8 a, bf16x8 b, f32x16 c) {
  return __builtin_amdgcn_mfma_f32_32x32x16_bf16(a, b, c, 0, 0, 0);
}

__device__ __forceinline__ void gl_lds16(const bf16* g, bf16* l) {
  __builtin_amdgcn_global_load_lds(
      (const __attribute__((address_space(1))) void*)(g),
      (__attribute__((address_space(3))) void*)(l), 16, 0, 0);
}
__device__ __forceinline__ void gl_lds4(const float* g, float* l) {
  __builtin_amdgcn_global_load_lds(
      (const __attribute__((address_space(1))) void*)(g),
      (__attribute__((address_space(3))) void*)(l), 4, 0, 0);
}

// ---------------- bias table: table[h][d] in exp2 (log2e-scaled) domain ----------------
__global__ void hope_bias_kernel(const float* __restrict__ pi, float* __restrict__ table) {
  int idx = blockIdx.x * blockDim.x + threadIdx.x;
  if (idx >= 1024 * NH) return;
  int h = idx >> 10, d = idx & 1023;
  float s = 0.f;
  if (h < 8) {
    int p0 = h * 32;
    for (int t = 0; t < 32; ++t) {
      float f = expf(-(float)(p0 + t) * (9.210340371976184f / 512.0f));
      float theta = (float)d * f;
      s += cosf(theta) + sinf(theta);
    }
  } else {
    int p0 = (h - 8) * 32;
    for (int t = 0; t < 32; ++t)
      s += pi[(p0 + t) * 2] + pi[(p0 + t) * 2 + 1];
  }
  table[h * 1024 + d] = s * LOG2E;
}

// ---------------- merged f32 -> bf16 convert ----------------
__global__ void cvt3_kernel(const float* __restrict__ a, bf16* __restrict__ oa, int na,
                            const float* __restrict__ b, bf16* __restrict__ ob, int nb,
                            const float* __restrict__ c, bf16* __restrict__ oc, int nc) {
  int i = (blockIdx.x * blockDim.x + threadIdx.x) * 4;
  const float* src; bf16* dst; int off;
  if (i < na) { src = a; dst = oa; off = i; }
  else if (i < na + nb) { src = b; dst = ob; off = i - na; }
  else if (i < na + nb + nc) { src = c; dst = oc; off = i - na - nb; }
  else return;
  float4 v = *reinterpret_cast<const float4*>(src + off);
  bf16x4 o;
  o[0] = (bf16)v.x; o[1] = (bf16)v.y; o[2] = (bf16)v.z; o[3] = (bf16)v.w;
  *reinterpret_cast<bf16x4*>(dst + off) = o;
}

// ================= 256x128 GEMM, BK=32, tri-buffered, 72KB LDS, mfma32 inner =================
__device__ __forceinline__ void stageA32(const bf16* __restrict__ G, int gr0, int t,
                                         bf16* D, int tid) {
  const int k0 = t * 32;
#pragma unroll
  for (int c = 0; c < 2; ++c) {
    const int idx = c * 512 + tid;
    const int row = idx >> 2, cg = idx & 3;
    const int scg = cg ^ (row & 3) ^ ((row >> 2) & 3);
    gl_lds16(&G[(size_t)(gr0 + row) * 1024 + k0 + scg * 8],
             D + (size_t)(c * 512 + (tid & 448)) * 8);
  }
}
__device__ __forceinline__ void stageB32(const bf16* __restrict__ G, int gr0, int t,
                                         bf16* D, int tid) {
  const int k0 = t * 32;
  const int row = tid >> 2, cg = tid & 3;
  const int scg = cg ^ (row & 3) ^ ((row >> 2) & 3);
  gl_lds16(&G[(size_t)(gr0 + row) * 1024 + k0 + scg * 8],
           D + (size_t)(tid & 448) * 8);
}

template<bool STG, int WAIT>
__device__ __forceinline__ void ktile32(bf16* SA, bf16* SDn,
    const bf16* __restrict__ A, const bf16* __restrict__ Bt,
    int m0, int n0, int t2,
    f32x16 (&acc)[2][2], int tid, int wr, int wc, int ql, int hi) {
  bf16* SB = SA + 8192;
  const int f = (ql & 3) ^ ((ql >> 2) & 3);
  bf16x8 aF[2][2], bF[2][2];
#pragma unroll
  for (int bi = 0; bi < 2; ++bi)
#pragma unroll
    for (int st = 0; st < 2; ++st) {
      const int slot = (st * 2 + hi) ^ f;
      aF[bi][st] = *reinterpret_cast<const bf16x8*>(
          &SA[(wr * 64 + bi * 32 + ql) * 32 + slot * 8]);
      bF[bi][st] = *reinterpret_cast<const bf16x8*>(
          &SB[(wc * 64 + bi * 32 + ql) * 32 + slot * 8]);
    }
  if (STG) {
    stageA32(A, m0, t2, SDn, tid);
    stageB32(Bt, n0, t2, SDn + 8192, tid);
  }
#pragma unroll
  for (int st = 0; st < 2; ++st)
#pragma unroll
    for (int bi = 0; bi < 2; ++bi)
#pragma unroll
      for (int bj = 0; bj < 2; ++bj)
        acc[bi][bj] = mfma32(aF[bi][st], bF[bj][st], acc[bi][bj]);
  if (WAIT == 3)      asm volatile("s_waitcnt vmcnt(3)" ::: "memory");
  else if (WAIT == 0) asm volatile("s_waitcnt vmcnt(0)" ::: "memory");
  __builtin_amdgcn_s_barrier();
}

__device__ __forceinline__ void gemmN_mainloop(
    bf16* S, const bf16* __restrict__ A, const bf16* __restrict__ Bt,
    int m0, int n0, f32x16 (&acc)[2][2],
    int tid, int wr, int wc, int ql, int hi) {
  bf16* B0 = S;
  bf16* B1 = S + 12288;
  bf16* B2 = S + 24576;
  stageA32(A, m0, 0, B0, tid);
  stageB32(Bt, n0, 0, B0 + 8192, tid);
  stageA32(A, m0, 1, B1, tid);
  stageB32(Bt, n0, 1, B1 + 8192, tid);
  asm volatile("s_waitcnt vmcnt(3)" ::: "memory");
  __builtin_amdgcn_s_barrier();
#pragma unroll 1
  for (int gq = 0; gq < 10; ++gq) {
    const int t = gq * 3;
    ktile32<true, 3>(B0, B2, A, Bt, m0, n0, t + 2, acc, tid, wr, wc, ql, hi);
    ktile32<true, 3>(B1, B0, A, Bt, m0, n0, t + 3, acc, tid, wr, wc, ql, hi);
    ktile32<true, 3>(B2, B1, A, Bt, m0, n0, t + 4, acc, tid, wr, wc, ql, hi);
  }
  ktile32<false, 0>(B0, B2, A, Bt, m0, n0, 0, acc, tid, wr, wc, ql, hi);
  ktile32<false, -1>(B1, B0, A, Bt, m0, n0, 0, acc, tid, wr, wc, ql, hi);
}

// ---------------- QKV projection: grid 768 = 3 exact rounds (2 blocks/CU) ----------------
__global__ __launch_bounds__(512, 4) void gemm_qkv8_kernel(
    const bf16* __restrict__ xb, const bf16* __restrict__ wb,
    const float* __restrict__ bias,
    bf16* __restrict__ Q, bf16* __restrict__ K, bf16* __restrict__ Vt) {
  extern __shared__ bf16 S[];
  const int tid = threadIdx.x;
  const int lane = tid & 63, wave = tid >> 6;
  const int wr = wave >> 1, wc = wave & 1;
  const int ql = lane & 31, hi = lane >> 5;
  const int wg = blockIdx.x;
  const int xcd = wg & 7, r = wg >> 3;
  const int sc = r / 48, t = r % 48;
  const int mi_ = t / 12, ni_ = sc * 12 + (t % 12);
  const int m0 = (xcd * 4 + mi_) * 256;
  const int n0 = ni_ * 128;

  f32x16 acc[2][2];
#pragma unroll
  for (int i = 0; i < 2; ++i)
#pragma unroll
    for (int j = 0; j < 2; ++j)
#pragma unroll
      for (int r4 = 0; r4 < 16; ++r4) acc[i][j][r4] = 0.f;

  gemmN_mainloop(S, xb, wb, m0, n0, acc, tid, wr, wc, ql, hi);

  const int c3 = n0 >> 10;
  const int bb = m0 >> 10;
#pragma unroll
  for (int bi = 0; bi < 2; ++bi) {
#pragma unroll
    for (int bj = 0; bj < 2; ++bj) {
      const int col = n0 + wc * 64 + bj * 32 + ql;
      const float bv = bias[col];
      const int hh = (col & 1023) >> 6;
      const int dd = col & 63;
      const size_t bhh = (size_t)(bb * NH + hh);
#pragma unroll
      for (int g4 = 0; g4 < 4; ++g4) {
        const int t0 = (m0 & 1023) + wr * 64 + bi * 32 + 8 * g4 + 4 * hi;
        if (c3 == 2) {
          bf16x4 pk;
#pragma unroll
          for (int rr = 0; rr < 4; ++rr) pk[rr] = (bf16)(acc[bi][bj][g4 * 4 + rr] + bv);
          *reinterpret_cast<bf16x4*>(&Vt[(bhh * HD + dd) * T_SEQ + t0]) = pk;
        } else {
          bf16* dst = (c3 == 0) ? Q : K;
#pragma unroll
          for (int rr = 0; rr < 4; ++rr)
            dst[(bhh * T_SEQ + t0 + rr) * HD + dd] = (bf16)(acc[bi][bj][g4 * 4 + rr] + bv);
        }
      }
    }
  }
}

// ---------------- output projection: grid 256 = 1 exact round ----------------
__global__ __launch_bounds__(512, 4) void gemm_proj8_kernel(
    const bf16* __restrict__ Ob, const bf16* __restrict__ wb,
    const float* __restrict__ bias, float* __restrict__ out) {
  extern __shared__ bf16 S[];
  const int tid = threadIdx.x;
  const int lane = tid & 63, wave = tid >> 6;
  const int wr = wave >> 1, wc = wave & 1;
  const int ql = lane & 31, hi = lane >> 5;
  const int wg = blockIdx.x;
  const int L = (wg & 7) * 32 + (wg >> 3);
  const int n0 = (L % 8) * 128;
  const int m0 = (L / 8) * 256;

  f32x16 acc[2][2];
#pragma unroll
  for (int i = 0; i < 2; ++i)
#pragma unroll
    for (int j = 0; j < 2; ++j)
#pragma unroll
      for (int r4 = 0; r4 < 16; ++r4) acc[i][j][r4] = 0.f;

  gemmN_mainloop(S, Ob, wb, m0, n0, acc, tid, wr, wc, ql, hi);

#pragma unroll
  for (int bi = 0; bi < 2; ++bi) {
#pragma unroll
    for (int bj = 0; bj < 2; ++bj) {
      const int col = n0 + wc * 64 + bj * 32 + ql;
      const float bv = bias[col];
#pragma unroll
      for (int g4 = 0; g4 < 4; ++g4) {
        const int row = m0 + wr * 64 + bi * 32 + 8 * g4 + 4 * hi;
#pragma unroll
        for (int rr = 0; rr < 4; ++rr)
          out[(size_t)(row + rr) * DM + col] = acc[bi][bj][g4 * 4 + rr] + bv;
      }
    }
  }
}

// ---------------- causal flash attention, swapped-operand 32x32 + LDS bias window ----------------
__device__ __forceinline__ uint2 pk4f(float a, float b, float c, float d) {
  bf16x4 v; v[0] = (bf16)a; v[1] = (bf16)b; v[2] = (bf16)c; v[3] = (bf16)d;
  uint2 u; __builtin_memcpy(&u, &v, 8); return u;
}

__global__ __launch_bounds__(256) void attn_kernel(
    const bf16* __restrict__ Q, const bf16* __restrict__ K,
    const bf16* __restrict__ Vt, const float* __restrict__ table,
    bf16* __restrict__ O)
{
  __shared__ bf16 Ks[2][64 * 64];
  __shared__ bf16 Vs[2][64 * 64];
  __shared__ float win[2][256];

  const int tid = threadIdx.x;
  const int lane = tid & 63;
  const int wq = tid >> 6;
  const int ql = lane & 31;
  const int hi = lane >> 5;
  const int ch = lane & 7;

  const int w = blockIdx.x;
  const int xcd = w & 7, idx = w >> 3;
  const int bh = xcd * 16 + (idx & 15);
  const int qt = 7 - (idx >> 4);
  const int h = bh & 15, b = bh >> 4;
  const int q0 = qt * 128;
  const int nkt = 2 * qt + 2;

  const bf16* Qp = Q + (size_t)bh * (T_SEQ * HD);
  const bf16* Kp = K + (size_t)bh * (T_SEQ * HD);
  const bf16* Vp = Vt + (size_t)bh * (HD * T_SEQ);
  const float* tb = table + h * 1024;

  const int qg = q0 + wq * 32 + ql;

  bf16x8 qf[4];
#pragma unroll
  for (int cs = 0; cs < 4; ++cs)
    qf[cs] = *reinterpret_cast<const bf16x8*>(&Qp[(size_t)qg * HD + cs * 16 + hi * 8]);

  f32x16 o0, o1;
#pragma unroll
  for (int r = 0; r < 16; ++r) { o0[r] = 0.f; o1[r] = 0.f; }
  float m_ = -1e30f, l_ = 0.f;

  const int srow = wq * 16;
  const int lrow = lane >> 3;

  auto stage = [&](int kt, int buf) {
#pragma unroll
    for (int i = 0; i < 2; ++i) {
      const int r0 = srow + i * 8;
      const int row = r0 + lrow;
      gl_lds16(&Kp[(size_t)(kt * 64 + row) * HD + 8 * (ch ^ (row & 7))],
               &Ks[buf][r0 * 64]);
      gl_lds16(&Vp[(size_t)row * T_SEQ + kt * 64 + 8 * (ch ^ (row & 7))],
               &Vs[buf][r0 * 64]);
    }
    gl_lds4(&tb[q0 - kt * 64 - 96 + tid], &win[buf][wq * 64]);
  };

  stage(0, 0);
  __syncthreads();

  for (int kt = 0; kt < nkt; ++kt) {
    const int buf = kt & 1;

    const float* wp = &win[buf][wq * 32 + ql - 4 * hi];
    float bias0[16], bias1[16];
#pragma unroll
    for (int r = 0; r < 16; ++r) {
      const int cr = (r & 3) + 8 * (r >> 2);
      bias0[r] = wp[96 - cr];
      bias1[r] = wp[64 - cr];
    }

    if (kt + 1 < nkt) stage(kt + 1, buf ^ 1);

    f32x16 st0, st1;
#pragma unroll
    for (int r = 0; r < 16; ++r) { st0[r] = 0.f; st1[r] = 0.f; }
    __builtin_amdgcn_s_setprio(1);
#pragma unroll
    for (int cs = 0; cs < 4; ++cs) {
      bf16x8 k0 = *reinterpret_cast<const bf16x8*>(&Ks[buf][ql * 64 + (((2 * cs + hi) ^ ch) * 8)]);
      bf16x8 k1 = *reinterpret_cast<const bf16x8*>(&Ks[buf][(32 + ql) * 64 + (((2 * cs + hi) ^ ch) * 8)]);
      st0 = mfma32(k0, qf[cs], st0);
      st1 = mfma32(k1, qf[cs], st1);
    }
    __builtin_amdgcn_s_setprio(0);

    const float SCALE2 = 0.125f * LOG2E;
    const int C2 = qg - kt * 64 - 4 * hi;
#pragma unroll
    for (int r = 0; r < 16; ++r) {
      const int cr = (r & 3) + 8 * (r >> 2);
      float v0 = (cr <= C2)      ? st0[r] * SCALE2 + bias0[r] : -1e30f;
      float v1 = (cr + 32 <= C2) ? st1[r] * SCALE2 + bias1[r] : -1e30f;
      st0[r] = v0; st1[r] = v1;
    }
    float t8[8];
#pragma unroll
    for (int j = 0; j < 8; ++j)
      t8[j] = fmaxf(fmaxf(st0[j], st0[j + 8]), fmaxf(st1[j], st1[j + 8]));
#pragma unroll
    for (int j = 0; j < 4; ++j) t8[j] = fmaxf(t8[j], t8[j + 4]);
    float pmax = fmaxf(fmaxf(t8[0], t8[1]), fmaxf(t8[2], t8[3]));
    pmax = fmaxf(pmax, __shfl_xor(pmax, 32));
    const float mnew = fmaxf(m_, pmax);
    const float corr = exp2f(m_ - mnew);
    m_ = mnew;
    float s0 = 0.f, s1 = 0.f;
#pragma unroll
    for (int r = 0; r < 16; ++r) {
      float e0 = exp2f(st0[r] - mnew); st0[r] = e0; s0 += e0;
      float e1 = exp2f(st1[r] - mnew); st1[r] = e1; s1 += e1;
    }
    float sum = s0 + s1;
    sum += __shfl_xor(sum, 32);
    l_ = l_ * corr + sum;
#pragma unroll
    for (int r = 0; r < 16; ++r) { o0[r] *= corr; o1[r] *= corr; }

    auto mkfrag = [&](const f32x16& p, int u) -> bf16x8 {
      uint2 A = pk4f(p[8 * u + 0], p[8 * u + 1], p[8 * u + 2], p[8 * u + 3]);
      uint2 B = pk4f(p[8 * u + 4], p[8 * u + 5], p[8 * u + 6], p[8 * u + 7]);
      uint2 send; send.x = hi ? A.x : B.x; send.y = hi ? A.y : B.y;
      uint2 recv; recv.x = __shfl_xor(send.x, 32); recv.y = __shfl_xor(send.y, 32);
      uint4 wf;
      wf.x = hi ? recv.x : A.x;  wf.y = hi ? recv.y : A.y;
      wf.z = hi ? B.x : recv.x;  wf.w = hi ? B.y : recv.y;
      bf16x8 fr; __builtin_memcpy(&fr, &wf, 16); return fr;
    };
    bf16x8 f0 = mkfrag(st0, 0);
    bf16x8 f1 = mkfrag(st0, 1);
    bf16x8 f2 = mkfrag(st1, 0);
    bf16x8 f3 = mkfrag(st1, 1);

    __builtin_amdgcn_s_setprio(1);
#pragma unroll
    for (int s = 0; s < 4; ++s) {
      bf16x8 vf0 = *reinterpret_cast<const bf16x8*>(&Vs[buf][ql * 64 + (((2 * s + hi) ^ ch) * 8)]);
      bf16x8 vf1 = *reinterpret_cast<const bf16x8*>(&Vs[buf][(32 + ql) * 64 + (((2 * s + hi) ^ ch) * 8)]);
      bf16x8 pf = (s == 0) ? f0 : (s == 1) ? f1 : (s == 2) ? f2 : f3;
      o0 = mfma32(vf0, pf, o0);
      o1 = mfma32(vf1, pf, o1);
    }
    __builtin_amdgcn_s_setprio(0);

    __syncthreads();
  }

  const float inv = 1.0f / l_;
  const size_t base = ((size_t)(b * T_SEQ + qg)) * DM + h * HD;
#pragma unroll
  for (int r4 = 0; r4 < 4; ++r4) {
    bf16x4 p0, p1;
#pragma unroll
    for (int j = 0; j < 4; ++j) {
      p0[j] = (bf16)(o0[r4 * 4 + j] * inv);
      p1[j] = (bf16)(o1[r4 * 4 + j] * inv);
    }
    *reinterpret_cast<bf16x4*>(&O[base + 8 * r4 + 4 * hi]) = p0;
    *reinterpret_cast<bf16x4*>(&O[base + 32 + 8 * r4 + 4 * hi]) = p1;
  }
}

extern "C" void kernel_launch(void* const* d_in, const int* in_sizes, int n_in,
                              void* d_out, int out_size, void* d_ws, size_t ws_size,
                              hipStream_t stream) {
  const float* x      = (const float*)d_in[0];
  const float* w_qkv  = (const float*)d_in[1];
  const float* b_qkv  = (const float*)d_in[2];
  const float* w_proj = (const float*)d_in[3];
  const float* b_proj = (const float*)d_in[4];
  const float* pos_in = (const float*)d_in[5];
  float* out = (float*)d_out;

  char* ws = (char*)d_ws;
  bf16* xb     = (bf16*)(ws);                         // 16 MB (reused as Ob)
  bf16* wqkvb  = (bf16*)(ws + 16777216);              //  6 MB
  bf16* wprojb = (bf16*)(ws + 23068672);              //  2 MB
  bf16* Qb     = (bf16*)(ws + 25165824);              // 16 MB
  bf16* Kb     = (bf16*)(ws + 41943040);              // 16 MB
  bf16* Vtb    = (bf16*)(ws + 58720256);              // 16 MB
  float* table = (float*)(ws + 75497472);             // 64 KB
  bf16* Ob = xb;

  static bool attr_done = false;
  if (!attr_done) {
    hipFuncSetAttribute((const void*)gemm_qkv8_kernel,
                        hipFuncAttributeMaxDynamicSharedMemorySize, 73728);
    hipFuncSetAttribute((const void*)gemm_proj8_kernel,
                        hipFuncAttributeMaxDynamicSharedMemorySize, 73728);
    attr_done = true;
  }

  const int nx = 8 * T_SEQ * DM, nwq = 3 * DM * DM, nwp = DM * DM;
  hope_bias_kernel<<<64, 256, 0, stream>>>(pos_in, table);
  cvt3_kernel<<<(nx + nwq + nwp) / 1024, 256, 0, stream>>>(
      x, xb, nx, w_qkv, wqkvb, nwq, w_proj, wprojb, nwp);

  gemm_qkv8_kernel<<<768, 512, 73728, stream>>>(xb, wqkvb, b_qkv, Qb, Kb, Vtb);
  attn_kernel<<<1024, 256, 0, stream>>>(Qb, Kb, Vtb, table, Ob);
  gemm_proj8_kernel<<<256, 512, 73728, stream>>>(Ob, wprojb, b_proj, out);
}